// Round 14
// baseline (1491.868 us; speedup 1.0000x reference)
//
#include <hip/hip_runtime.h>

// ScaledDotProductAttention: B=4 H=16 S=2048 DK=128, fp32 in, int32 mask.
// Outputs (concatenated in d_out): out (B,H,S,DK) fp32 then weights (B,H,S,S) fp32.
//
// R13: R11 (passing, 705us) + ONLY the proven piece of R12: odd-dword LDS strides.
//  - sKd row stride 136 -> 138 f16 (69 dwords, odd): QK b128 reads 8-way -> <=2-way
//    (R12 verified: conflicts 5.45e7 -> 8.4e6)
//  - sV row stride 72 -> 74 f16 (37 dwords, odd): same fix for PV reads
//  - everything else identical to R11 (sV staging back, R11 pass-B structure)
// R12 lesson: V-direct-from-L2 multiplied per-wave V traffic x8 (+3.8GB L2, +609us).

constexpr int Sc = 2048, Dc = 128;
constexpr int BHc = 64;
constexpr long OUTE = (long)BHc * Sc * Dc;   // out elems (start of weights region)
constexpr long KVE  = (long)BHc * Sc * Dc;   // elems per K/V plane
constexpr int QBR = 128;                      // q rows per main block
constexpr int NQT = Sc / QBR;                 // 16
constexpr int NBLK = BHc * NQT;               // 1024
#define SCALEF 0.088388347648318447f          // 1/sqrt(128)

typedef __attribute__((ext_vector_type(4))) float f32x4;
typedef _Float16 f16x8 __attribute__((ext_vector_type(8)));

static __device__ __forceinline__ f16x8 loadcvt8h(const float* __restrict__ p) {
  float4 a = *(const float4*)p;
  float4 b = *(const float4*)(p + 4);
  f16x8 r;
  r[0] = (_Float16)a.x; r[1] = (_Float16)a.y; r[2] = (_Float16)a.z; r[3] = (_Float16)a.w;
  r[4] = (_Float16)b.x; r[5] = (_Float16)b.y; r[6] = (_Float16)b.z; r[7] = (_Float16)b.w;
  return r;
}

// ---- prepass 1: K fp32 -> fp16, [bh][k][d]. (known-good)
__global__ __launch_bounds__(256)
void kconv_kernel(const float* __restrict__ K, _Float16* __restrict__ Kh) {
  long i = ((long)blockIdx.x * 256 + threadIdx.x) * 8;
  f16x8 v = loadcvt8h(K + i);
  *(f16x8*)(Kh + i) = v;
}

// ---- prepass 2: V fp32 [bh][k][d] -> fp16 transposed [bh][d][k]. (known-good)
__global__ __launch_bounds__(256)
void vtrans_kernel(const float* __restrict__ V, _Float16* __restrict__ Vt) {
  __shared__ _Float16 sT[Dc][64 + 2];
  const int bh = blockIdx.x >> 5;
  const int kt = blockIdx.x & 31;
  const int tid = threadIdx.x;
  const float* vb = V + ((long)bh * Sc + kt * 64) * Dc;
  #pragma unroll
  for (int i = 0; i < 8; i++) {
    int e = tid + i * 256;
    int ki = e >> 5;
    int dq = (e & 31) * 4;
    float4 f = *(const float4*)(vb + (long)ki * Dc + dq);
    sT[dq + 0][ki] = (_Float16)f.x;
    sT[dq + 1][ki] = (_Float16)f.y;
    sT[dq + 2][ki] = (_Float16)f.z;
    sT[dq + 3][ki] = (_Float16)f.w;
  }
  __syncthreads();
  #pragma unroll
  for (int i = 0; i < 4; i++) {
    int chunk = tid + i * 256;
    int d = chunk >> 3;
    int kc = (chunk & 7) * 8;
    f16x8 o;
    #pragma unroll
    for (int j = 0; j < 8; j++) o[j] = sT[d][kc + j];
    *(f16x8*)(Vt + ((long)bh * Dc + d) * Sc + kt * 64 + kc) = o;
  }
}

// ---- main kernel: 1024 blocks x 512 threads, QBR=128 rows, k-chunks of 64 via LDS.
__global__ __launch_bounds__(512, 4)
void sdpa_main(const float* __restrict__ Qg, const int* __restrict__ Mg,
               float* __restrict__ Og, const _Float16* __restrict__ Kh,
               const _Float16* __restrict__ Vt, unsigned* __restrict__ msk) {
  __shared__ __align__(16) _Float16 sKd[2][64][138];  // dbuf K, odd-dword stride, 34.5 KB
  __shared__ __align__(16) _Float16 sV[128][74];      // odd-dword stride, 18.9 KB
  __shared__ __align__(16) _Float16 sPw[8][16][76];   // P bounce, 19 KB
  __shared__ float sRinv[QBR];

  const int bid0 = blockIdx.x;
  const int bid  = (bid0 & 7) * (NBLK >> 3) + (bid0 >> 3);   // XCD swizzle (1024%8==0)
  const int bh = bid >> 4;
  const int qt = bid & (NQT - 1);

  const int tid  = threadIdx.x;
  const int lane = tid & 63;
  const int w = tid >> 6;          // wave 0..7 owns q-rows w*16..w*16+15
  const int g = lane >> 4;
  const int c = lane & 15;

  // Q A-frags: lane holds Q[qrow = w*16 + c][d = ch*32 + g*8 + j]
  f16x8 aq[4];
  {
    const float* qp = Qg + ((long)bh * Sc + (long)qt * QBR + w * 16 + c) * Dc + g * 8;
    #pragma unroll
    for (int ch = 0; ch < 4; ch++) aq[ch] = loadcvt8h(qp + ch * 32);
  }

  const _Float16* Kplane = Kh + (long)bh * Sc * Dc;
  const _Float16* Vplane = Vt + (long)bh * Dc * Sc;
  const int* Mwave = Mg + ((long)bh * Sc + (long)qt * QBR + w * 16 + g * 4) * Sc;
  unsigned* mskB = msk + (long)bid0 * (16 * 512);   // per-block stash; thread-private words

  // staging geometry: 1024 16B-units each for K and V; thread covers unit tid, tid+512
  const int kr0 = tid >> 4, kd0 = tid & 15;    // K: row 0..31 (+32), dcol8 0..15
  const int vr0 = tid >> 3, vc0 = tid & 7;     // V: drow 0..63 (+64), kcol8 0..7

  auto loadK = [&](int cc, f16x8& a, f16x8& b) {
    a = *(const f16x8*)(Kplane + (long)(cc * 64 + kr0) * Dc + kd0 * 8);
    b = *(const f16x8*)(Kplane + (long)(cc * 64 + kr0 + 32) * Dc + kd0 * 8);
  };
  auto stageK = [&](int p, const f16x8& a, const f16x8& b) {
    *(f16x8*)&sKd[p][kr0][kd0 * 8] = a;
    *(f16x8*)&sKd[p][kr0 + 32][kd0 * 8] = b;
  };
  auto loadV = [&](int cc, f16x8& a, f16x8& b) {
    a = *(const f16x8*)(Vplane + (long)vr0 * Sc + cc * 64 + vc0 * 8);
    b = *(const f16x8*)(Vplane + (long)(vr0 + 64) * Sc + cc * 64 + vc0 * 8);
  };
  auto stageV = [&](const f16x8& a, const f16x8& b) {
    *(f16x8*)&sV[vr0][vc0 * 8] = a;
    *(f16x8*)&sV[vr0 + 64][vc0 * 8] = b;
  };
  auto loadM = [&](int (*dst)[4], int cc) {
    const int* mp = Mwave + cc * 64 + c;
    #pragma unroll
    for (int nt = 0; nt < 4; nt++)
      #pragma unroll
      for (int r = 0; r < 4; r++)
        dst[nt][r] = mp[(long)r * Sc + nt * 16];
  };
  auto packbits = [&](const int (*mv)[4]) -> unsigned {
    unsigned bits = 0;
    #pragma unroll
    for (int nt = 0; nt < 4; nt++)
      #pragma unroll
      for (int r = 0; r < 4; r++)
        bits |= (mv[nt][r] != 0 ? 1u : 0u) << (nt * 4 + r);
    return bits;
  };

  // QK^T 16x16 tile nt from sKd[p]
  auto qkTile = [&](int p, int nt) -> f32x4 {
    const _Float16* kb = &sKd[p][nt * 16 + c][g * 8];
    f16x8 b0 = *(const f16x8*)kb;
    f16x8 b1 = *(const f16x8*)(kb + 32);
    f16x8 b2 = *(const f16x8*)(kb + 64);
    f16x8 b3 = *(const f16x8*)(kb + 96);
    f32x4 s = {0.f, 0.f, 0.f, 0.f};
    s = __builtin_amdgcn_mfma_f32_16x16x32_f16(aq[0], b0, s, 0, 0, 0);
    s = __builtin_amdgcn_mfma_f32_16x16x32_f16(aq[1], b1, s, 0, 0, 0);
    s = __builtin_amdgcn_mfma_f32_16x16x32_f16(aq[2], b2, s, 0, 0, 0);
    s = __builtin_amdgcn_mfma_f32_16x16x32_f16(aq[3], b3, s, 0, 0, 0);
    return s;
  };

  // ---- pass A: rowsums of exp(masked QK^T); mask bits packed to ws.
  // 2-chunk ping-pong (R11, passing): 1 barrier/chunk, K+mask one chunk early.
  float rs[4] = {0.f, 0.f, 0.f, 0.f};
  {
    f16x8 ka0, kb0, ka1, kb1;
    int mv0[4][4], mv1[4][4];
    auto bodyA = [&](int p, unsigned bits) {
      #pragma unroll
      for (int nt = 0; nt < 4; nt++) {
        f32x4 s = qkTile(p, nt);
        #pragma unroll
        for (int r = 0; r < 4; r++) {
          float e = ((bits >> (nt * 4 + r)) & 1u) ? __expf(s[r] * SCALEF) : 0.f;
          rs[r] += (float)(_Float16)e;   // fp16-rounded, matches pass B exactly
        }
      }
    };
    loadK(0, ka0, kb0);
    loadM(mv0, 0);
    for (int cc = 0; cc < 32; cc += 2) {
      stageK(0, ka0, kb0);
      __syncthreads();                          // buf 0 visible
      loadK(cc + 1, ka1, kb1);
      loadM(mv1, cc + 1);
      const unsigned bits0 = packbits(mv0);
      bodyA(0, bits0);
      stageK(1, ka1, kb1);
      __syncthreads();                          // buf 1 visible
      if (cc + 2 < 32) {
        loadK(cc + 2, ka0, kb0);
        loadM(mv0, cc + 2);
      }
      const unsigned bits1 = packbits(mv1);
      mskB[((cc >> 1) << 9) + tid] = bits0 | (bits1 << 16);
      bodyA(1, bits1);
    }
  }
  #pragma unroll
  for (int r = 0; r < 4; r++) {
    float x = rs[r];
    x += __shfl_xor(x, 1);
    x += __shfl_xor(x, 2);
    x += __shfl_xor(x, 4);
    x += __shfl_xor(x, 8);
    if (c == 0) sRinv[w * 16 + g * 4 + r] = (x > 0.f) ? (1.f / x) : 0.f;
  }
  __syncthreads();                             // sRinv visible
  const float rinvW = sRinv[w * 16 + (lane >> 2)];
  float rinvO[4];
  #pragma unroll
  for (int r = 0; r < 4; r++) rinvO[r] = sRinv[w * 16 + g * 4 + r];

  // ---- pass B: recompute S -> P bounce -> weights write + PV accumulate
  f32x4 oacc[8];
  #pragma unroll
  for (int dt = 0; dt < 8; dt++) oacc[dt] = (f32x4){0.f, 0.f, 0.f, 0.f};
  float* wbase = Og + OUTE + ((long)bh * Sc + (long)qt * QBR + w * 16) * Sc;
  const int wr = lane >> 2;        // weights row within wave tile
  const int wq = lane & 3;         // weights col quarter (16 cols)

  {
    f16x8 ka, kb2, va, vb2;
    loadK(0, ka, kb2);
    loadV(0, va, vb2);
    unsigned bp = mskB[tid];                   // pair 0 (L3-hot)
    unsigned bpn = 0;
    for (int cc = 0; cc < 32; cc++) {
      __syncthreads();
      stageK(0, ka, kb2);
      stageV(va, vb2);
      __syncthreads();
      if (cc + 1 < 32) {
        loadK(cc + 1, ka, kb2);
        loadV(cc + 1, va, vb2);
      }
      if ((cc & 1) == 0 && (cc >> 1) + 1 < 16)
        bpn = mskB[(((cc >> 1) + 1) << 9) + tid];   // prefetch next pair
      const unsigned bits = (cc & 1) ? (bp >> 16) : (bp & 0xffffu);
      // QK^T + exp -> bounce (identical compute to pass A)
      #pragma unroll
      for (int nt = 0; nt < 4; nt++) {
        f32x4 s = qkTile(0, nt);
        #pragma unroll
        for (int r = 0; r < 4; r++) {
          float e = ((bits >> (nt * 4 + r)) & 1u) ? __expf(s[r] * SCALEF) : 0.f;
          sPw[w][g * 4 + r][nt * 16 + c] = (_Float16)e;
        }
      }
      // weights: row wr, cols wq*16..+15 (wave-local LDS dep; lgkmcnt ordered)
      {
        f16x8 p0 = *(const f16x8*)&sPw[w][wr][wq * 16];
        f16x8 p1 = *(const f16x8*)&sPw[w][wr][wq * 16 + 8];
        float* dst = wbase + (long)wr * Sc + cc * 64 + wq * 16;
        float4 o0, o1, o2, o3;
        o0.x = (float)p0[0] * rinvW; o0.y = (float)p0[1] * rinvW;
        o0.z = (float)p0[2] * rinvW; o0.w = (float)p0[3] * rinvW;
        o1.x = (float)p0[4] * rinvW; o1.y = (float)p0[5] * rinvW;
        o1.z = (float)p0[6] * rinvW; o1.w = (float)p0[7] * rinvW;
        o2.x = (float)p1[0] * rinvW; o2.y = (float)p1[1] * rinvW;
        o2.z = (float)p1[2] * rinvW; o2.w = (float)p1[3] * rinvW;
        o3.x = (float)p1[4] * rinvW; o3.y = (float)p1[5] * rinvW;
        o3.z = (float)p1[6] * rinvW; o3.w = (float)p1[7] * rinvW;
        *(float4*)dst = o0;
        *(float4*)(dst + 4) = o1;
        *(float4*)(dst + 8) = o2;
        *(float4*)(dst + 12) = o3;
      }
      // PV: A-frags from bounce, B-frags from sV
      f16x8 pa0 = *(const f16x8*)&sPw[w][c][g * 8];
      f16x8 pa1 = *(const f16x8*)&sPw[w][c][32 + g * 8];
      #pragma unroll
      for (int dt = 0; dt < 8; dt++) {
        const _Float16* vb = &sV[dt * 16 + c][g * 8];
        f16x8 v0 = *(const f16x8*)vb;
        f16x8 v1 = *(const f16x8*)(vb + 32);
        oacc[dt] = __builtin_amdgcn_mfma_f32_16x16x32_f16(pa0, v0, oacc[dt], 0, 0, 0);
        oacc[dt] = __builtin_amdgcn_mfma_f32_16x16x32_f16(pa1, v1, oacc[dt], 0, 0, 0);
      }
      if (cc & 1) bp = bpn;
    }
  }

  // ---- epilogue: out = oacc * rinv
  float* ob = Og + ((long)bh * Sc + (long)qt * QBR + w * 16 + g * 4) * Dc;
  #pragma unroll
  for (int r = 0; r < 4; r++) {
    #pragma unroll
    for (int dt = 0; dt < 8; dt++) {
      ob[(long)r * Dc + dt * 16 + c] = oacc[dt][r] * rinvO[r];
    }
  }
}

// ---- fallback (ws too small): simple, correct, slow. One wave per q-row.
__global__ __launch_bounds__(256)
void sdpa_naive(const float* __restrict__ Qg, const float* __restrict__ Kg,
                const float* __restrict__ Vg, const int* __restrict__ Mg,
                float* __restrict__ Og) {
  __shared__ float sE[4][Sc];
  const int bh = blockIdx.x >> 9;
  const int rg = blockIdx.x & 511;
  const int wv = threadIdx.x >> 6, ln = threadIdx.x & 63;
  const int qrow = rg * 4 + wv;
  const float* qp = Qg + ((long)bh * Sc + qrow) * Dc;
  const int* mp = Mg + ((long)bh * Sc + qrow) * Sc;
  float rsum = 0.f;
  for (int k0 = 0; k0 < Sc; k0 += 64) {
    const int kcol = k0 + ln;
    const float* kp = Kg + ((long)bh * Sc + kcol) * Dc;
    float s = 0.f;
    for (int d = 0; d < Dc; d++) s += qp[d] * kp[d];
    float e = (mp[kcol] != 0) ? __expf(s * SCALEF) : 0.f;
    e = (float)(_Float16)e;
    sE[wv][kcol] = e;
    rsum += e;
  }
  for (int o = 1; o < 64; o <<= 1) rsum += __shfl_xor(rsum, o);
  float oa = 0.f, ob2 = 0.f;
  for (int k = 0; k < Sc; k++) {
    const float e = sE[wv][k];
    const float* vp = Vg + ((long)bh * Sc + k) * Dc;
    oa += e * vp[ln];
    ob2 += e * vp[ln + 64];
  }
  const float ri = (rsum > 0.f) ? 1.f / rsum : 0.f;
  float* op = Og + ((long)bh * Sc + qrow) * Dc;
  op[ln] = oa * ri;
  op[ln + 64] = ob2 * ri;
  float* wb = Og + OUTE + ((long)bh * Sc + qrow) * Sc;
  for (int k = ln; k < Sc; k += 64) wb[k] = sE[wv][k] * ri;
}

extern "C" void kernel_launch(void* const* d_in, const int* in_sizes, int n_in,
                              void* d_out, int out_size, void* d_ws, size_t ws_size,
                              hipStream_t stream) {
  (void)in_sizes; (void)n_in; (void)out_size;
  const float* q = (const float*)d_in[0];
  const float* k = (const float*)d_in[1];
  const float* v = (const float*)d_in[2];
  const int* m = (const int*)d_in[3];
  float* out = (float*)d_out;

  // ws: Kh fp16 (33.5MB) | Vt fp16 (33.5MB) | mask bits (33.5MB) = 100,663,296 B
  const size_t need = 2UL * KVE * sizeof(_Float16) + (size_t)NBLK * 16 * 512 * 4;
  if (d_ws != nullptr && ws_size >= need) {
    _Float16* Kh = (_Float16*)d_ws;
    _Float16* Vt = Kh + KVE;
    unsigned* msk = (unsigned*)(Vt + KVE);
    hipLaunchKernelGGL(kconv_kernel, dim3((int)(KVE / 8 / 256)), dim3(256), 0, stream, k, Kh);
    hipLaunchKernelGGL(vtrans_kernel, dim3(BHc * 32), dim3(256), 0, stream, v, Vt);
    hipLaunchKernelGGL(sdpa_main, dim3(NBLK), dim3(512), 0, stream, q, m, out, Kh, Vt, msk);
  } else {
    hipLaunchKernelGGL(sdpa_naive, dim3(BHc * 512), dim3(256), 0, stream, q, k, v, m, out);
  }
}

// Round 15
// 704.141 us; speedup vs baseline: 2.1187x; 2.1187x over previous
//
#include <hip/hip_runtime.h>

// ScaledDotProductAttention: B=4 H=16 S=2048 DK=128, fp32 in, int32 mask.
// Outputs (concatenated in d_out): out (B,H,S,DK) fp32 then weights (B,H,S,S) fp32.
//
// R14: REVERT to R11 verbatim (empirical best, 705us).
// R12/R13 root cause (recorded): odd-dword LDS row strides (276B/148B) break the
// 16B alignment of f16x8 LDS accesses -> compiler splits ds_{read,write}_b128 into
// b32/b64 ops -> LDS op count x2-4 -> ~2x regression. LDS pads must stay multiples
// of 16B. The SQ_LDS_BANK_CONFLICT ~5.4e7 on this kernel is largely the b128
// minimum-cycle serialization (64 lanes x 16B >= 8 cy), not a removable tax.
//
// Structure: QBR=128 block, 8 waves; pass A (rowsums + mask-bit pack to ws) with
// dbuf-K 1-barrier ping-pong; pass B (recompute S -> sPw bounce -> weights + PV)
// with single-buffer K/V staging, 2 barriers/chunk; prepasses K->fp16, V->fp16^T.

constexpr int Sc = 2048, Dc = 128;
constexpr int BHc = 64;
constexpr long OUTE = (long)BHc * Sc * Dc;   // out elems (start of weights region)
constexpr long KVE  = (long)BHc * Sc * Dc;   // elems per K/V plane
constexpr int QBR = 128;                      // q rows per main block
constexpr int NQT = Sc / QBR;                 // 16
constexpr int NBLK = BHc * NQT;               // 1024
#define SCALEF 0.088388347648318447f          // 1/sqrt(128)

typedef __attribute__((ext_vector_type(4))) float f32x4;
typedef _Float16 f16x8 __attribute__((ext_vector_type(8)));

static __device__ __forceinline__ f16x8 loadcvt8h(const float* __restrict__ p) {
  float4 a = *(const float4*)p;
  float4 b = *(const float4*)(p + 4);
  f16x8 r;
  r[0] = (_Float16)a.x; r[1] = (_Float16)a.y; r[2] = (_Float16)a.z; r[3] = (_Float16)a.w;
  r[4] = (_Float16)b.x; r[5] = (_Float16)b.y; r[6] = (_Float16)b.z; r[7] = (_Float16)b.w;
  return r;
}

// ---- prepass 1: K fp32 -> fp16, [bh][k][d]. (known-good)
__global__ __launch_bounds__(256)
void kconv_kernel(const float* __restrict__ K, _Float16* __restrict__ Kh) {
  long i = ((long)blockIdx.x * 256 + threadIdx.x) * 8;
  f16x8 v = loadcvt8h(K + i);
  *(f16x8*)(Kh + i) = v;
}

// ---- prepass 2: V fp32 [bh][k][d] -> fp16 transposed [bh][d][k]. (known-good)
__global__ __launch_bounds__(256)
void vtrans_kernel(const float* __restrict__ V, _Float16* __restrict__ Vt) {
  __shared__ _Float16 sT[Dc][64 + 2];
  const int bh = blockIdx.x >> 5;
  const int kt = blockIdx.x & 31;
  const int tid = threadIdx.x;
  const float* vb = V + ((long)bh * Sc + kt * 64) * Dc;
  #pragma unroll
  for (int i = 0; i < 8; i++) {
    int e = tid + i * 256;
    int ki = e >> 5;
    int dq = (e & 31) * 4;
    float4 f = *(const float4*)(vb + (long)ki * Dc + dq);
    sT[dq + 0][ki] = (_Float16)f.x;
    sT[dq + 1][ki] = (_Float16)f.y;
    sT[dq + 2][ki] = (_Float16)f.z;
    sT[dq + 3][ki] = (_Float16)f.w;
  }
  __syncthreads();
  #pragma unroll
  for (int i = 0; i < 4; i++) {
    int chunk = tid + i * 256;
    int d = chunk >> 3;
    int kc = (chunk & 7) * 8;
    f16x8 o;
    #pragma unroll
    for (int j = 0; j < 8; j++) o[j] = sT[d][kc + j];
    *(f16x8*)(Vt + ((long)bh * Dc + d) * Sc + kt * 64 + kc) = o;
  }
}

// ---- main kernel: 1024 blocks x 512 threads, QBR=128 rows, k-chunks of 64 via LDS.
__global__ __launch_bounds__(512, 4)
void sdpa_main(const float* __restrict__ Qg, const int* __restrict__ Mg,
               float* __restrict__ Og, const _Float16* __restrict__ Kh,
               const _Float16* __restrict__ Vt, unsigned* __restrict__ msk) {
  __shared__ __align__(16) _Float16 sKd[2][64][136];  // dbuf K, 16B-aligned rows
  __shared__ __align__(16) _Float16 sV[128][72];      // 16B-aligned rows, 18.4 KB
  __shared__ __align__(16) _Float16 sPw[8][16][76];   // P bounce (b16 writes; pad ok)
  __shared__ float sRinv[QBR];

  const int bid0 = blockIdx.x;
  const int bid  = (bid0 & 7) * (NBLK >> 3) + (bid0 >> 3);   // XCD swizzle (1024%8==0)
  const int bh = bid >> 4;
  const int qt = bid & (NQT - 1);

  const int tid  = threadIdx.x;
  const int lane = tid & 63;
  const int w = tid >> 6;          // wave 0..7 owns q-rows w*16..w*16+15
  const int g = lane >> 4;
  const int c = lane & 15;

  // Q A-frags: lane holds Q[qrow = w*16 + c][d = ch*32 + g*8 + j]
  f16x8 aq[4];
  {
    const float* qp = Qg + ((long)bh * Sc + (long)qt * QBR + w * 16 + c) * Dc + g * 8;
    #pragma unroll
    for (int ch = 0; ch < 4; ch++) aq[ch] = loadcvt8h(qp + ch * 32);
  }

  const _Float16* Kplane = Kh + (long)bh * Sc * Dc;
  const _Float16* Vplane = Vt + (long)bh * Dc * Sc;
  const int* Mwave = Mg + ((long)bh * Sc + (long)qt * QBR + w * 16 + g * 4) * Sc;
  unsigned* mskB = msk + (long)bid0 * (16 * 512);   // per-block stash; thread-private words

  // staging geometry: 1024 16B-units each for K and V; thread covers unit tid, tid+512
  const int kr0 = tid >> 4, kd0 = tid & 15;    // K: row 0..31 (+32), dcol8 0..15
  const int vr0 = tid >> 3, vc0 = tid & 7;     // V: drow 0..63 (+64), kcol8 0..7

  auto loadK = [&](int cc, f16x8& a, f16x8& b) {
    a = *(const f16x8*)(Kplane + (long)(cc * 64 + kr0) * Dc + kd0 * 8);
    b = *(const f16x8*)(Kplane + (long)(cc * 64 + kr0 + 32) * Dc + kd0 * 8);
  };
  auto stageK = [&](int p, const f16x8& a, const f16x8& b) {
    *(f16x8*)&sKd[p][kr0][kd0 * 8] = a;
    *(f16x8*)&sKd[p][kr0 + 32][kd0 * 8] = b;
  };
  auto loadV = [&](int cc, f16x8& a, f16x8& b) {
    a = *(const f16x8*)(Vplane + (long)vr0 * Sc + cc * 64 + vc0 * 8);
    b = *(const f16x8*)(Vplane + (long)(vr0 + 64) * Sc + cc * 64 + vc0 * 8);
  };
  auto stageV = [&](const f16x8& a, const f16x8& b) {
    *(f16x8*)&sV[vr0][vc0 * 8] = a;
    *(f16x8*)&sV[vr0 + 64][vc0 * 8] = b;
  };
  auto loadM = [&](int (*dst)[4], int cc) {
    const int* mp = Mwave + cc * 64 + c;
    #pragma unroll
    for (int nt = 0; nt < 4; nt++)
      #pragma unroll
      for (int r = 0; r < 4; r++)
        dst[nt][r] = mp[(long)r * Sc + nt * 16];
  };
  auto packbits = [&](const int (*mv)[4]) -> unsigned {
    unsigned bits = 0;
    #pragma unroll
    for (int nt = 0; nt < 4; nt++)
      #pragma unroll
      for (int r = 0; r < 4; r++)
        bits |= (mv[nt][r] != 0 ? 1u : 0u) << (nt * 4 + r);
    return bits;
  };

  // QK^T 16x16 tile nt from sKd[p]
  auto qkTile = [&](int p, int nt) -> f32x4 {
    const _Float16* kb = &sKd[p][nt * 16 + c][g * 8];
    f16x8 b0 = *(const f16x8*)kb;
    f16x8 b1 = *(const f16x8*)(kb + 32);
    f16x8 b2 = *(const f16x8*)(kb + 64);
    f16x8 b3 = *(const f16x8*)(kb + 96);
    f32x4 s = {0.f, 0.f, 0.f, 0.f};
    s = __builtin_amdgcn_mfma_f32_16x16x32_f16(aq[0], b0, s, 0, 0, 0);
    s = __builtin_amdgcn_mfma_f32_16x16x32_f16(aq[1], b1, s, 0, 0, 0);
    s = __builtin_amdgcn_mfma_f32_16x16x32_f16(aq[2], b2, s, 0, 0, 0);
    s = __builtin_amdgcn_mfma_f32_16x16x32_f16(aq[3], b3, s, 0, 0, 0);
    return s;
  };

  // ---- pass A: rowsums of exp(masked QK^T); mask bits packed to ws.
  // 2-chunk ping-pong: 1 barrier/chunk, K+mask one chunk early.
  float rs[4] = {0.f, 0.f, 0.f, 0.f};
  {
    f16x8 ka0, kb0, ka1, kb1;
    int mv0[4][4], mv1[4][4];
    auto bodyA = [&](int p, unsigned bits) {
      #pragma unroll
      for (int nt = 0; nt < 4; nt++) {
        f32x4 s = qkTile(p, nt);
        #pragma unroll
        for (int r = 0; r < 4; r++) {
          float e = ((bits >> (nt * 4 + r)) & 1u) ? __expf(s[r] * SCALEF) : 0.f;
          rs[r] += (float)(_Float16)e;   // fp16-rounded, matches pass B exactly
        }
      }
    };
    loadK(0, ka0, kb0);
    loadM(mv0, 0);
    for (int cc = 0; cc < 32; cc += 2) {
      stageK(0, ka0, kb0);
      __syncthreads();                          // buf 0 visible
      loadK(cc + 1, ka1, kb1);
      loadM(mv1, cc + 1);
      const unsigned bits0 = packbits(mv0);
      bodyA(0, bits0);
      stageK(1, ka1, kb1);
      __syncthreads();                          // buf 1 visible
      if (cc + 2 < 32) {
        loadK(cc + 2, ka0, kb0);
        loadM(mv0, cc + 2);
      }
      const unsigned bits1 = packbits(mv1);
      mskB[((cc >> 1) << 9) + tid] = bits0 | (bits1 << 16);
      bodyA(1, bits1);
    }
  }
  #pragma unroll
  for (int r = 0; r < 4; r++) {
    float x = rs[r];
    x += __shfl_xor(x, 1);
    x += __shfl_xor(x, 2);
    x += __shfl_xor(x, 4);
    x += __shfl_xor(x, 8);
    if (c == 0) sRinv[w * 16 + g * 4 + r] = (x > 0.f) ? (1.f / x) : 0.f;
  }
  __syncthreads();                             // sRinv visible
  const float rinvW = sRinv[w * 16 + (lane >> 2)];
  float rinvO[4];
  #pragma unroll
  for (int r = 0; r < 4; r++) rinvO[r] = sRinv[w * 16 + g * 4 + r];

  // ---- pass B: recompute S -> P bounce -> weights write + PV accumulate
  f32x4 oacc[8];
  #pragma unroll
  for (int dt = 0; dt < 8; dt++) oacc[dt] = (f32x4){0.f, 0.f, 0.f, 0.f};
  float* wbase = Og + OUTE + ((long)bh * Sc + (long)qt * QBR + w * 16) * Sc;
  const int wr = lane >> 2;        // weights row within wave tile
  const int wq = lane & 3;         // weights col quarter (16 cols)

  {
    f16x8 ka, kb2, va, vb2;
    loadK(0, ka, kb2);
    loadV(0, va, vb2);
    unsigned bp = mskB[tid];                   // pair 0 (L3-hot)
    unsigned bpn = 0;
    for (int cc = 0; cc < 32; cc++) {
      __syncthreads();
      stageK(0, ka, kb2);
      stageV(va, vb2);
      __syncthreads();
      if (cc + 1 < 32) {
        loadK(cc + 1, ka, kb2);
        loadV(cc + 1, va, vb2);
      }
      if ((cc & 1) == 0 && (cc >> 1) + 1 < 16)
        bpn = mskB[(((cc >> 1) + 1) << 9) + tid];   // prefetch next pair
      const unsigned bits = (cc & 1) ? (bp >> 16) : (bp & 0xffffu);
      // QK^T + exp -> bounce (identical compute to pass A)
      #pragma unroll
      for (int nt = 0; nt < 4; nt++) {
        f32x4 s = qkTile(0, nt);
        #pragma unroll
        for (int r = 0; r < 4; r++) {
          float e = ((bits >> (nt * 4 + r)) & 1u) ? __expf(s[r] * SCALEF) : 0.f;
          sPw[w][g * 4 + r][nt * 16 + c] = (_Float16)e;
        }
      }
      // weights: row wr, cols wq*16..+15 (wave-local LDS dep; lgkmcnt ordered)
      {
        f16x8 p0 = *(const f16x8*)&sPw[w][wr][wq * 16];
        f16x8 p1 = *(const f16x8*)&sPw[w][wr][wq * 16 + 8];
        float* dst = wbase + (long)wr * Sc + cc * 64 + wq * 16;
        float4 o0, o1, o2, o3;
        o0.x = (float)p0[0] * rinvW; o0.y = (float)p0[1] * rinvW;
        o0.z = (float)p0[2] * rinvW; o0.w = (float)p0[3] * rinvW;
        o1.x = (float)p0[4] * rinvW; o1.y = (float)p0[5] * rinvW;
        o1.z = (float)p0[6] * rinvW; o1.w = (float)p0[7] * rinvW;
        o2.x = (float)p1[0] * rinvW; o2.y = (float)p1[1] * rinvW;
        o2.z = (float)p1[2] * rinvW; o2.w = (float)p1[3] * rinvW;
        o3.x = (float)p1[4] * rinvW; o3.y = (float)p1[5] * rinvW;
        o3.z = (float)p1[6] * rinvW; o3.w = (float)p1[7] * rinvW;
        *(float4*)dst = o0;
        *(float4*)(dst + 4) = o1;
        *(float4*)(dst + 8) = o2;
        *(float4*)(dst + 12) = o3;
      }
      // PV: A-frags from bounce, B-frags from sV
      f16x8 pa0 = *(const f16x8*)&sPw[w][c][g * 8];
      f16x8 pa1 = *(const f16x8*)&sPw[w][c][32 + g * 8];
      #pragma unroll
      for (int dt = 0; dt < 8; dt++) {
        const _Float16* vb = &sV[dt * 16 + c][g * 8];
        f16x8 v0 = *(const f16x8*)vb;
        f16x8 v1 = *(const f16x8*)(vb + 32);
        oacc[dt] = __builtin_amdgcn_mfma_f32_16x16x32_f16(pa0, v0, oacc[dt], 0, 0, 0);
        oacc[dt] = __builtin_amdgcn_mfma_f32_16x16x32_f16(pa1, v1, oacc[dt], 0, 0, 0);
      }
      if (cc & 1) bp = bpn;
    }
  }

  // ---- epilogue: out = oacc * rinv
  float* ob = Og + ((long)bh * Sc + (long)qt * QBR + w * 16 + g * 4) * Dc;
  #pragma unroll
  for (int r = 0; r < 4; r++) {
    #pragma unroll
    for (int dt = 0; dt < 8; dt++) {
      ob[(long)r * Dc + dt * 16 + c] = oacc[dt][r] * rinvO[r];
    }
  }
}

// ---- fallback (ws too small): simple, correct, slow. One wave per q-row.
__global__ __launch_bounds__(256)
void sdpa_naive(const float* __restrict__ Qg, const float* __restrict__ Kg,
                const float* __restrict__ Vg, const int* __restrict__ Mg,
                float* __restrict__ Og) {
  __shared__ float sE[4][Sc];
  const int bh = blockIdx.x >> 9;
  const int rg = blockIdx.x & 511;
  const int wv = threadIdx.x >> 6, ln = threadIdx.x & 63;
  const int qrow = rg * 4 + wv;
  const float* qp = Qg + ((long)bh * Sc + qrow) * Dc;
  const int* mp = Mg + ((long)bh * Sc + qrow) * Sc;
  float rsum = 0.f;
  for (int k0 = 0; k0 < Sc; k0 += 64) {
    const int kcol = k0 + ln;
    const float* kp = Kg + ((long)bh * Sc + kcol) * Dc;
    float s = 0.f;
    for (int d = 0; d < Dc; d++) s += qp[d] * kp[d];
    float e = (mp[kcol] != 0) ? __expf(s * SCALEF) : 0.f;
    e = (float)(_Float16)e;
    sE[wv][kcol] = e;
    rsum += e;
  }
  for (int o = 1; o < 64; o <<= 1) rsum += __shfl_xor(rsum, o);
  float oa = 0.f, ob2 = 0.f;
  for (int k = 0; k < Sc; k++) {
    const float e = sE[wv][k];
    const float* vp = Vg + ((long)bh * Sc + k) * Dc;
    oa += e * vp[ln];
    ob2 += e * vp[ln + 64];
  }
  const float ri = (rsum > 0.f) ? 1.f / rsum : 0.f;
  float* op = Og + ((long)bh * Sc + qrow) * Dc;
  op[ln] = oa * ri;
  op[ln + 64] = ob2 * ri;
  float* wb = Og + OUTE + ((long)bh * Sc + qrow) * Sc;
  for (int k = ln; k < Sc; k += 64) wb[k] = sE[wv][k] * ri;
}

extern "C" void kernel_launch(void* const* d_in, const int* in_sizes, int n_in,
                              void* d_out, int out_size, void* d_ws, size_t ws_size,
                              hipStream_t stream) {
  (void)in_sizes; (void)n_in; (void)out_size;
  const float* q = (const float*)d_in[0];
  const float* k = (const float*)d_in[1];
  const float* v = (const float*)d_in[2];
  const int* m = (const int*)d_in[3];
  float* out = (float*)d_out;

  // ws: Kh fp16 (33.5MB) | Vt fp16 (33.5MB) | mask bits (33.5MB) = 100,663,296 B
  const size_t need = 2UL * KVE * sizeof(_Float16) + (size_t)NBLK * 16 * 512 * 4;
  if (d_ws != nullptr && ws_size >= need) {
    _Float16* Kh = (_Float16*)d_ws;
    _Float16* Vt = Kh + KVE;
    unsigned* msk = (unsigned*)(Vt + KVE);
    hipLaunchKernelGGL(kconv_kernel, dim3((int)(KVE / 8 / 256)), dim3(256), 0, stream, k, Kh);
    hipLaunchKernelGGL(vtrans_kernel, dim3(BHc * 32), dim3(256), 0, stream, v, Vt);
    hipLaunchKernelGGL(sdpa_main, dim3(NBLK), dim3(512), 0, stream, q, m, out, Kh, Vt, msk);
  } else {
    hipLaunchKernelGGL(sdpa_naive, dim3(BHc * 512), dim3(256), 0, stream, q, k, v, m, out);
  }
}